// Round 4
// baseline (5612.824 us; speedup 1.0000x reference)
//
#include <hip/hip_runtime.h>
#include <math.h>

namespace {

constexpr int kS = 1024, kHp = 8, kRp = 257;
constexpr float kEPS = 1e-5f;

enum { EPI_PLAIN = 0, EPI_GELU = 1, EPI_RESID = 2, EPI_SCORES = 3 };

typedef short bf16x8 __attribute__((ext_vector_type(8)));   // 8 bf16 in 4 VGPRs
typedef float f32x4 __attribute__((ext_vector_type(4)));

__device__ inline unsigned short f2b(float f) {              // f32 -> bf16 (RNE)
    unsigned u = __float_as_uint(f);
    u += 0x7FFFu + ((u >> 16) & 1u);
    return (unsigned short)(u >> 16);
}

// bf16-MFMA tiled GEMM: C[M,N] = A[M,K] @ B[K,N] (+bias)(+epilogue), f32 in/out.
// BT=true: B given as [N,K] row-major (compute A @ B^T).
// Batched via blockIdx.z: z -> (zb=z/Hin, zh=z%Hin), ptr += zb*s?b + zh*s?h.
// Tile 128x128, BK=32, 256 threads = 4 waves (2x2), wave tile 64x64.
// LDS: As[m][k], Bs[n][k], both k-contiguous, row stride 40 bf16 (80B).
template<bool BT, int EPI>
__global__ __launch_bounds__(256)
void gemm_mfma(const float* __restrict__ A, int lda, long long sAb, long long sAh,
               const float* __restrict__ Bm, int ldb, long long sBb, long long sBh,
               float* __restrict__ C, int ldc, long long sCb, long long sCh,
               const float* __restrict__ bias,
               const float* __restrict__ res, int ldres, long long sRb, long long sRh,
               const float* __restrict__ qrel, long long sQb, long long sQh,
               int M, int N, int K, int Hin, float scale)
{
    const int z = blockIdx.z;
    const int zb = z / Hin, zh = z % Hin;
    A  += zb * sAb + zh * sAh;
    Bm += zb * sBb + zh * sBh;
    C  += zb * sCb + zh * sCh;
    if (EPI == EPI_RESID)  res  += zb * sRb + zh * sRh;
    if (EPI == EPI_SCORES) qrel += zb * sQb + zh * sQh;

    __shared__ unsigned short As[128 * 40];
    __shared__ unsigned short Bs[128 * 40];

    const int m0 = blockIdx.y * 128, n0 = blockIdx.x * 128;
    const int t = threadIdx.x;
    const int lane = t & 63, wid = t >> 6;
    const int wr = wid >> 1, wc = wid & 1;      // wave grid 2x2
    const int lr = lane & 15, lg = lane >> 4;   // frag col / k-group

    const f32x4 zero4 = {0.f, 0.f, 0.f, 0.f};
    f32x4 acc[4][4];
    #pragma unroll
    for (int i = 0; i < 4; ++i)
        #pragma unroll
        for (int j = 0; j < 4; ++j) acc[i][j] = zero4;

    const int sr  = t >> 3;          // 0..31
    const int sc4 = (t & 7) << 2;    // 0,4,...,28

    for (int k0 = 0; k0 < K; k0 += 32) {
        // ---- stage A: [128 m][32 k] f32 -> bf16, k-contiguous
        #pragma unroll
        for (int rr = 0; rr < 128; rr += 32) {
            const int row = rr + sr;
            const int gm = m0 + row;
            float4 av = make_float4(0.f, 0.f, 0.f, 0.f);
            if (gm < M) av = *(const float4*)&A[(long long)gm * lda + k0 + sc4];
            ushort4 w = make_ushort4(f2b(av.x), f2b(av.y), f2b(av.z), f2b(av.w));
            *(ushort4*)&As[row * 40 + sc4] = w;
        }
        // ---- stage B -> Bs[n][k]
        if (!BT) {   // B[K][N]: read along n (coalesced), transpose into LDS
            #pragma unroll
            for (int nn = 0; nn < 128; nn += 32) {
                const int gn = n0 + nn + sc4;
                float4 bv = make_float4(0.f, 0.f, 0.f, 0.f);
                if (gn < N) bv = *(const float4*)&Bm[(long long)(k0 + sr) * ldb + gn];
                Bs[(nn + sc4 + 0) * 40 + sr] = f2b(bv.x);
                Bs[(nn + sc4 + 1) * 40 + sr] = f2b(bv.y);
                Bs[(nn + sc4 + 2) * 40 + sr] = f2b(bv.z);
                Bs[(nn + sc4 + 3) * 40 + sr] = f2b(bv.w);
            }
        } else {     // B^T[N][K]: read along k, same orientation as LDS
            #pragma unroll
            for (int nn = 0; nn < 128; nn += 32) {
                const int n = nn + sr;
                const int gn = n0 + n;
                float4 bv = make_float4(0.f, 0.f, 0.f, 0.f);
                if (gn < N) bv = *(const float4*)&Bm[(long long)gn * ldb + k0 + sc4];
                ushort4 w = make_ushort4(f2b(bv.x), f2b(bv.y), f2b(bv.z), f2b(bv.w));
                *(ushort4*)&Bs[n * 40 + sc4] = w;
            }
        }
        __syncthreads();

        // ---- fragments + 16 MFMAs (one BK=32 step)
        const int abase = (wr * 64 + lr) * 40 + lg * 8;
        const int bbase = (wc * 64 + lr) * 40 + lg * 8;
        bf16x8 af[4], bfr[4];
        #pragma unroll
        for (int i = 0; i < 4; ++i) af[i]  = *(const bf16x8*)&As[abase + i * 640];
        #pragma unroll
        for (int j = 0; j < 4; ++j) bfr[j] = *(const bf16x8*)&Bs[bbase + j * 640];
        #pragma unroll
        for (int i = 0; i < 4; ++i)
            #pragma unroll
            for (int j = 0; j < 4; ++j)
                acc[i][j] = __builtin_amdgcn_mfma_f32_16x16x32_bf16(
                                af[i], bfr[j], acc[i][j], 0, 0, 0);
        __syncthreads();
    }

    // ---- epilogue: C row = lg*4+r, col = lr within each 16x16 fragment
    #pragma unroll
    for (int i = 0; i < 4; ++i) {
        #pragma unroll
        for (int j = 0; j < 4; ++j) {
            #pragma unroll
            for (int r = 0; r < 4; ++r) {
                const int gm = m0 + wr * 64 + i * 16 + lg * 4 + r;
                const int gn = n0 + wc * 64 + j * 16 + lr;
                if (gm >= M || gn >= N) continue;
                float vv = acc[i][j][r];
                if (bias) vv += bias[gn];
                if (EPI == EPI_GELU) {
                    vv = 0.5f * vv * (1.f + erff(vv * 0.70710678118654752f));
                } else if (EPI == EPI_RESID) {
                    vv += res[(long long)gm * ldres + gn];
                } else if (EPI == EPI_SCORES) {
                    int dd = gn - gm;                    // k - q
                    dd = dd < -128 ? -128 : (dd > 128 ? 128 : dd);
                    vv = (vv + qrel[(long long)gm * kRp + dd + 128]) * scale;
                }
                C[(long long)gm * ldc + gn] = vv;
            }
        }
    }
}

__global__ __launch_bounds__(256)
void ln_kernel(const float* __restrict__ x, const float* __restrict__ g,
               const float* __restrict__ b, float* __restrict__ y, int ncol)
{
    const long long row = blockIdx.x;
    const float* xr = x + row * ncol;
    float s = 0.f, s2 = 0.f;
    for (int c = threadIdx.x; c < ncol; c += 256) {
        const float v = xr[c];
        s += v; s2 += v * v;
    }
    #pragma unroll
    for (int off = 32; off; off >>= 1) {
        s  += __shfl_xor(s, off);
        s2 += __shfl_xor(s2, off);
    }
    __shared__ float rs[4], rs2[4];
    const int w = threadIdx.x >> 6, lane = threadIdx.x & 63;
    if (lane == 0) { rs[w] = s; rs2[w] = s2; }
    __syncthreads();
    s  = rs[0] + rs[1] + rs[2] + rs[3];
    s2 = rs2[0] + rs2[1] + rs2[2] + rs2[3];
    const float inv_n = 1.f / (float)ncol;
    const float mean = s * inv_n;
    const float var = s2 * inv_n - mean * mean;      // biased var, matches jnp.var
    const float inv = 1.f / sqrtf(var + kEPS);
    float* yr = y + row * ncol;
    for (int c = threadIdx.x; c < ncol; c += 256)
        yr[c] = (xr[c] - mean) * inv * g[c] + b[c];
}

// softmax over rows of length 1024; 256 threads, 4 elems/thread, in-place
__global__ __launch_bounds__(256)
void softmax_kernel(float* __restrict__ sc)
{
    const long long row = blockIdx.x;
    float* sr = sc + row * 1024;
    const int c0 = threadIdx.x << 2;
    float4 vv = *(float4*)&sr[c0];
    float mx = fmaxf(fmaxf(vv.x, vv.y), fmaxf(vv.z, vv.w));
    #pragma unroll
    for (int off = 32; off; off >>= 1) mx = fmaxf(mx, __shfl_xor(mx, off));
    __shared__ float rm[4], rsum[4];
    const int w = threadIdx.x >> 6, lane = threadIdx.x & 63;
    if (lane == 0) rm[w] = mx;
    __syncthreads();
    mx = fmaxf(fmaxf(rm[0], rm[1]), fmaxf(rm[2], rm[3]));
    const float e0 = expf(vv.x - mx), e1 = expf(vv.y - mx),
                e2 = expf(vv.z - mx), e3 = expf(vv.w - mx);
    float s = e0 + e1 + e2 + e3;
    #pragma unroll
    for (int off = 32; off; off >>= 1) s += __shfl_xor(s, off);
    if (lane == 0) rsum[w] = s;
    __syncthreads();
    s = rsum[0] + rsum[1] + rsum[2] + rsum[3];
    const float inv = 1.f / s;
    const float4 o = make_float4(e0 * inv, e1 * inv, e2 * inv, e3 * inv);
    *(float4*)&sr[c0] = o;
}

// h0[tok, e] = embed[x[tok]][e] + PE(s, e)   (tok = b*S + s, E=256)
__global__ __launch_bounds__(256)
void embed_pe_kernel(const int* __restrict__ x, const float* __restrict__ embed,
                     float* __restrict__ h0)
{
    const int idx = blockIdx.x * 256 + threadIdx.x;   // NT*E = 524288
    const int tok = idx >> 8;
    const int e = idx & 255;
    const int s = tok & (kS - 1);
    const int id = x[tok];
    const float cfac = -9.21034037197618f / 256.f;    // -ln(10000)/E
    const float div = expf((float)(e & ~1) * cfac);
    const float ang = (float)s * div;
    const float pe = (e & 1) ? cosf(ang) : sinf(ang);
    h0[idx] = embed[(long long)id * 256 + e] + pe;
}

template<bool BT, int EPI>
void launch_gemm(hipStream_t st,
                 const float* A, int lda, long long sAb, long long sAh,
                 const float* Bm, int ldb, long long sBb, long long sBh,
                 float* C, int ldc, long long sCb, long long sCh,
                 const float* bias,
                 const float* res, int ldres, long long sRb, long long sRh,
                 const float* qrel, long long sQb, long long sQh,
                 int M, int N, int K, int Hin, int batches, float scale)
{
    dim3 g((N + 127) / 128, (M + 127) / 128, batches), b(256);
    gemm_mfma<BT, EPI><<<g, b, 0, st>>>(A, lda, sAb, sAh, Bm, ldb, sBb, sBh,
                                        C, ldc, sCb, sCh, bias,
                                        res, ldres, sRb, sRh, qrel, sQb, sQh,
                                        M, N, K, Hin, scale);
}

} // namespace

extern "C" void kernel_launch(void* const* d_in, const int* in_sizes, int n_in,
                              void* d_out, int out_size, void* d_ws, size_t ws_size,
                              hipStream_t stream)
{
    (void)in_sizes; (void)n_in; (void)out_size; (void)ws_size;
    const int*   x     = (const int*)  d_in[0];
    const float* embed = (const float*)d_in[1];
    const float* Win   = (const float*)d_in[2];
    const float* b_in  = (const float*)d_in[3];
    const float* ln1g  = (const float*)d_in[4];
    const float* ln1b  = (const float*)d_in[5];
    const float* Wq    = (const float*)d_in[6];
    const float* bq    = (const float*)d_in[7];
    const float* Wk    = (const float*)d_in[8];
    const float* bk    = (const float*)d_in[9];
    const float* Wv    = (const float*)d_in[10];
    const float* bv    = (const float*)d_in[11];
    const float* Wo    = (const float*)d_in[12];
    const float* bo    = (const float*)d_in[13];
    const float* rel   = (const float*)d_in[14];
    const float* ln2g  = (const float*)d_in[15];
    const float* ln2b  = (const float*)d_in[16];
    const float* W1    = (const float*)d_in[17];
    const float* b1    = (const float*)d_in[18];
    const float* W2    = (const float*)d_in[19];
    const float* b2    = (const float*)d_in[20];
    const float* lnfg  = (const float*)d_in[21];
    const float* lnfb  = (const float*)d_in[22];
    const float* Wout  = (const float*)d_in[23];
    const float* bout  = (const float*)d_in[24];
    float* out = (float*)d_out;

    const long long NT = 2048;                 // B*S tokens
    float* ws   = (float*)d_ws;
    float* h    = ws;                          // [2048, 512]
    float* a    = h    + NT * 512;             // [2048, 512] (LN out / attn out)
    float* q    = a    + NT * 512;             // [2048, 512] == [B,S,H,D]
    float* k    = q    + NT * 512;
    float* v    = k    + NT * 512;
    float* qrel = v    + NT * 512;             // [16, 1024, 257]
    float* sc   = qrel + (long long)16 * 1024 * kRp;   // [16, 1024, 1024]
    float* mid  = sc;                          // [2048, 2048] aliases scores
    float* h0   = q;                           // [2048, 256] aliases q (pre-layers)

    const long long sTok = (long long)kS * 512;   // per-b stride in [N,HID] bufs
    const long long sQb  = (long long)kHp * kS * kRp, sQh = (long long)kS * kRp;
    const long long sScb = (long long)kHp * kS * kS, sSch = (long long)kS * kS;

    // ---- embedding + positional encoding -> h0 [2048,256]
    embed_pe_kernel<<<(NT * 256) / 256, 256, 0, stream>>>(x, embed, h0);
    // ---- input projection: h = h0 @ Win + b_in
    launch_gemm<false, EPI_PLAIN>(stream, h0, 256, 0, 0, Win, 512, 0, 0,
                                  h, 512, 0, 0, b_in, nullptr, 0, 0, 0,
                                  nullptr, 0, 0, 2048, 512, 256, 1, 1, 1.f);

    for (int l = 0; l < 6; ++l) {
        const float* wq = Wq + (long long)l * 512 * 512;
        const float* wk = Wk + (long long)l * 512 * 512;
        const float* wv = Wv + (long long)l * 512 * 512;
        const float* wo = Wo + (long long)l * 512 * 512;
        const float* w1 = W1 + (long long)l * 512 * 2048;
        const float* w2 = W2 + (long long)l * 2048 * 512;
        const float* relT = rel + (long long)l * kRp * 64;

        // a = LN1(h)
        ln_kernel<<<2048, 256, 0, stream>>>(h, ln1g + l * 512, ln1b + l * 512, a, 512);
        // q/k/v = a @ W + b   (stored [B,S,H,D] == [N,HID])
        launch_gemm<false, EPI_PLAIN>(stream, a, 512, 0, 0, wq, 512, 0, 0,
                                      q, 512, 0, 0, bq + l * 512, nullptr, 0, 0, 0,
                                      nullptr, 0, 0, 2048, 512, 512, 1, 1, 1.f);
        launch_gemm<false, EPI_PLAIN>(stream, a, 512, 0, 0, wk, 512, 0, 0,
                                      k, 512, 0, 0, bk + l * 512, nullptr, 0, 0, 0,
                                      nullptr, 0, 0, 2048, 512, 512, 1, 1, 1.f);
        launch_gemm<false, EPI_PLAIN>(stream, a, 512, 0, 0, wv, 512, 0, 0,
                                      v, 512, 0, 0, bv + l * 512, nullptr, 0, 0, 0,
                                      nullptr, 0, 0, 2048, 512, 512, 1, 1, 1.f);
        // qrel[bh, s, r] = q[bh, s, :] . relT[r, :]   (A @ Bt^T, batched over 16)
        launch_gemm<true, EPI_PLAIN>(stream, q, 512, sTok, 64, relT, 64, 0, 0,
                                     qrel, kRp, sQb, sQh, nullptr, nullptr, 0, 0, 0,
                                     nullptr, 0, 0, 1024, kRp, 64, 8, 16, 1.f);
        // scores = (q @ k^T + qrel[gather]) * 1/sqrt(D)
        launch_gemm<true, EPI_SCORES>(stream, q, 512, sTok, 64, k, 512, sTok, 64,
                                      sc, 1024, sScb, sSch, nullptr, nullptr, 0, 0, 0,
                                      qrel, sQb, sQh, 1024, 1024, 64, 8, 16, 0.125f);
        // softmax rows
        softmax_kernel<<<16 * 1024, 256, 0, stream>>>(sc);
        // a[b, s, h*64+d] = attn @ v    (per-bh GEMM, direct [B,S,HID] write)
        launch_gemm<false, EPI_PLAIN>(stream, sc, 1024, sScb, sSch, v, 512, sTok, 64,
                                      a, 512, sTok, 64, nullptr, nullptr, 0, 0, 0,
                                      nullptr, 0, 0, 1024, 64, 1024, 8, 16, 1.f);
        // h = h + a @ Wo + bo
        launch_gemm<false, EPI_RESID>(stream, a, 512, 0, 0, wo, 512, 0, 0,
                                      h, 512, 0, 0, bo + l * 512, h, 512, 0, 0,
                                      nullptr, 0, 0, 2048, 512, 512, 1, 1, 1.f);
        // a = LN2(h)
        ln_kernel<<<2048, 256, 0, stream>>>(h, ln2g + l * 512, ln2b + l * 512, a, 512);
        // mid = gelu(a @ W1 + b1)
        launch_gemm<false, EPI_GELU>(stream, a, 512, 0, 0, w1, 2048, 0, 0,
                                     mid, 2048, 0, 0, b1 + l * 2048, nullptr, 0, 0, 0,
                                     nullptr, 0, 0, 2048, 2048, 512, 1, 1, 1.f);
        // h = h + mid @ W2 + b2
        launch_gemm<false, EPI_RESID>(stream, mid, 2048, 0, 0, w2, 512, 0, 0,
                                      h, 512, 0, 0, b2 + l * 512, h, 512, 0, 0,
                                      nullptr, 0, 0, 2048, 512, 2048, 1, 1, 1.f);
    }

    // final LN + output projection
    ln_kernel<<<2048, 256, 0, stream>>>(h, lnfg, lnfb, a, 512);
    launch_gemm<false, EPI_PLAIN>(stream, a, 512, 0, 0, Wout, 32000, 0, 0,
                                  out, 32000, 0, 0, bout, nullptr, 0, 0, 0,
                                  nullptr, 0, 0, 2048, 32000, 512, 1, 1, 1.f);
}